// Round 10
// baseline (1640.249 us; speedup 1.0000x reference)
//
#include <hip/hip_runtime.h>
#include <hip/hip_cooperative_groups.h>
#include <math.h>

namespace cg = cooperative_groups;

#define B_ 4
#define L_ 1024
#define DM 256
#define DIN 512
#define NST 16
#define DTR 16
#define CHK 64          // number of chunks over L
#define CT (L_ / CHK)   // chunk length = 16

typedef short short8 __attribute__((ext_vector_type(8)));
typedef float float4v __attribute__((ext_vector_type(4)));

__device__ __forceinline__ float softplusf(float x) {
    return (x > 20.f) ? x : log1pf(__expf(x));
}
__device__ __forceinline__ float siluf(float x) {
    return x / (1.f + __expf(-x));
}
__device__ __forceinline__ unsigned short f2bf(float f) {  // RNE bf16
    unsigned int u = __float_as_uint(f);
    u = (u + 0x7fffu + ((u >> 16) & 1u)) >> 16;
    return (unsigned short)u;
}

// two-value block reduction (sum) over 256 threads = 4 waves
__device__ __forceinline__ void block_reduce2(float& a, float& q) {
    #pragma unroll
    for (int off = 32; off > 0; off >>= 1) {
        a += __shfl_down(a, off);
        q += __shfl_down(q, off);
    }
    __shared__ float sa[4], sq[4];
    int lane = threadIdx.x & 63, w = threadIdx.x >> 6;
    if (lane == 0) { sa[w] = a; sq[w] = q; }
    __syncthreads();
    a = sa[0] + sa[1] + sa[2] + sa[3];
    q = sq[0] + sq[1] + sq[2] + sq[3];
}

struct KParams {
    const float *x, *ipw, *ipb, *inw, *cw, *cb, *xpw, *dtw, *dtb,
                *alog, *dsk, *opw, *lnw, *lnb, *fnw, *fnb, *clw, *clb;
    float *hbuf, *xzbuf, *xcbuf, *dbcbuf, *Sbuf, *Hbuf, *partial, *out;
    unsigned short *yb16, *xcb16, *inw16, *xpw16, *opw16;
};

// One cooperative kernel for the whole net. Stages separated by grid.sync()
// (replaces ~30 dispatch boundaries). All stage bodies are verbatim ports of
// the round-9 standalone kernels, re-indexed as grid-stride loops.
__global__ __launch_bounds__(256, 2) void mega_kernel(KParams p)
{
    cg::grid_group gg = cg::this_grid();
    // LDS union: max stage = in_ln (64x264 + 64x72 shorts = 43008 B)
    __shared__ __align__(16) unsigned char smem[43008];
    const int tid = threadIdx.x;
    const int nb = gridDim.x;
    const int wave = tid >> 6;
    const int lane = tid & 63;
    const int m_l = lane & 15;
    const int q = lane >> 4;

    // ---- stage 0: weight f2bf + input projection ----
    {
        const int NIN = 4 * 1024 * DM, NXP = 4 * 48 * DIN, NOP = 4 * DM * DIN;
        for (int i = blockIdx.x * 256 + tid; i < NIN; i += nb * 256)
            p.inw16[i] = f2bf(p.inw[i]);
        for (int i = blockIdx.x * 256 + tid; i < NXP; i += nb * 256)
            p.xpw16[i] = f2bf(p.xpw[i]);
        for (int i = blockIdx.x * 256 + tid; i < NOP; i += nb * 256)
            p.opw16[i] = f2bf(p.opw[i]);
        for (int idx = blockIdx.x * 256 + tid; idx < B_ * L_ * DM; idx += nb * 256) {
            int d = idx & (DM - 1);
            int bl = idx >> 8;
            int l = bl & (L_ - 1);
            int b = bl >> 10;
            const float* xb = p.x + (size_t)b * 3 * L_;
            float acc = p.ipb[d];
            acc = fmaf(xb[0 * L_ + l], p.ipw[d * 3 + 0], acc);
            acc = fmaf(xb[1 * L_ + l], p.ipw[d * 3 + 1], acc);
            acc = fmaf(xb[2 * L_ + l], p.ipw[d * 3 + 2], acc);
            p.hbuf[idx] = acc;
        }
    }
    gg.sync();

    for (int layer = 0; layer < 4; ++layer) {
        const unsigned short* inw16 = p.inw16 + (size_t)layer * 1024 * DM;
        const unsigned short* xpw16 = p.xpw16 + (size_t)layer * 48 * DIN;
        const unsigned short* opw16 = p.opw16 + (size_t)layer * DM * DIN;
        const float* lw   = p.lnw + layer * DM;
        const float* lbv  = p.lnb + layer * DM;
        const float* cwp  = p.cw  + layer * DIN * 4;
        const float* cbp  = p.cb  + layer * DIN;
        const float* alog = p.alog + (size_t)layer * DIN * NST;
        const float* dtw  = p.dtw + layer * DIN * DTR;
        const float* dtb  = p.dtb + layer * DIN;
        const float* dsk  = p.dsk + layer * DIN;

        // ---- stage 1: fused LN + in_proj GEMM (64x64 tiles, 1024 units) ----
        {
            unsigned short (*As)[264] = (unsigned short (*)[264])smem;
            unsigned short (*Ws)[72]  = (unsigned short (*)[72])(smem + 64 * 264 * 2);
            const int sr = tid >> 3;
            const int sc = (tid & 7) * 8;
            for (int t = blockIdx.x; t < 16 * 64; t += nb) {
                const int n0 = (t & 15) * 64;
                const int m0 = (t >> 4) * 64;
                // phase 1: LN rows m0..m0+63 into As
                {
                    const int rg = lane >> 4;
                    const int c4 = lane & 15;
                    #pragma unroll
                    for (int pp = 0; pp < 4; ++pp) {
                        int r = pp * 16 + wave * 4 + rg;
                        const float* ap = p.hbuf + (size_t)(m0 + r) * DM;
                        float4 v[4];
                        float s = 0.f, qq = 0.f;
                        #pragma unroll
                        for (int i = 0; i < 4; ++i) {
                            v[i] = *(const float4*)(ap + i * 64 + c4 * 4);
                            s  += v[i].x + v[i].y + v[i].z + v[i].w;
                            qq += v[i].x * v[i].x + v[i].y * v[i].y
                                + v[i].z * v[i].z + v[i].w * v[i].w;
                        }
                        s += __shfl_xor(s, 1); qq += __shfl_xor(qq, 1);
                        s += __shfl_xor(s, 2); qq += __shfl_xor(qq, 2);
                        s += __shfl_xor(s, 4); qq += __shfl_xor(qq, 4);
                        s += __shfl_xor(s, 8); qq += __shfl_xor(qq, 8);
                        float mu = s * (1.f / DM);
                        float var = qq * (1.f / DM) - mu * mu;
                        float rs = rsqrtf(var + 1e-5f);
                        #pragma unroll
                        for (int i = 0; i < 4; ++i) {
                            int col = i * 64 + c4 * 4;
                            float4 wv = *(const float4*)(lw + col);
                            float4 bv = *(const float4*)(lbv + col);
                            unsigned short* dst = &As[r][col];
                            dst[0] = f2bf((v[i].x - mu) * rs * wv.x + bv.x);
                            dst[1] = f2bf((v[i].y - mu) * rs * wv.y + bv.y);
                            dst[2] = f2bf((v[i].z - mu) * rs * wv.z + bv.z);
                            dst[3] = f2bf((v[i].w - mu) * rs * wv.w + bv.w);
                        }
                    }
                }
                __syncthreads();
                float4v acc[4];
                #pragma unroll
                for (int j = 0; j < 4; ++j) acc[j] = (float4v)(0.f);
                for (int k0 = 0; k0 < DM; k0 += 64) {
                    *(short8*)&Ws[sr][sc] =
                        *(const short8*)(inw16 + (size_t)(n0 + sr) * DM + k0 + sc);
                    *(short8*)&Ws[sr + 32][sc] =
                        *(const short8*)(inw16 + (size_t)(n0 + sr + 32) * DM + k0 + sc);
                    __syncthreads();
                    #pragma unroll
                    for (int kk = 0; kk < 64; kk += 32) {
                        short8 a = *(const short8*)&As[wave * 16 + m_l][k0 + kk + q * 8];
                        #pragma unroll
                        for (int j4 = 0; j4 < 4; ++j4) {
                            short8 b = *(const short8*)&Ws[j4 * 16 + m_l][kk + q * 8];
                            acc[j4] = __builtin_amdgcn_mfma_f32_16x16x32_bf16(a, b, acc[j4], 0, 0, 0);
                        }
                    }
                    __syncthreads();
                }
                #pragma unroll
                for (int j4 = 0; j4 < 4; ++j4) {
                    int n = n0 + j4 * 16 + m_l;
                    #pragma unroll
                    for (int reg = 0; reg < 4; ++reg) {
                        int m = m0 + wave * 16 + q * 4 + reg;
                        p.xzbuf[(size_t)m * 1024 + n] = acc[j4][reg];
                    }
                }
            }
        }
        gg.sync();

        // ---- stage 2: conv + silu (elementwise) ----
        for (int idx = blockIdx.x * 256 + tid; idx < B_ * L_ * DIN; idx += nb * 256) {
            int d = idx & (DIN - 1);
            int bl = idx >> 9;
            int l = bl & (L_ - 1);
            int b = bl >> 10;
            float acc = cbp[d];
            #pragma unroll
            for (int k = 0; k < 4; ++k) {
                int ls = l - 3 + k;
                if (ls >= 0)
                    acc = fmaf(p.xzbuf[((size_t)(b * L_ + ls)) * (2 * DIN) + d],
                               cwp[d * 4 + k], acc);
            }
            float v = siluf(acc);
            p.xcbuf[idx] = v;
            p.xcb16[idx] = f2bf(v);
        }
        gg.sync();

        // ---- stage 3: x_proj GEMM (32x32 tiles, 256 units, N=48) ----
        {
            unsigned short (*As)[72] = (unsigned short (*)[72])smem;
            unsigned short (*Ws)[72] = (unsigned short (*)[72])(smem + 32 * 72 * 2);
            const int rw  = (wave & 1) * 16;
            const int cw2 = (wave >> 1) * 16;
            const int sr = tid >> 3;
            const int sc = (tid & 7) * 8;
            for (int t = blockIdx.x; t < 2 * (B_ * L_ / 32); t += nb) {
                const int n0 = (t & 1) * 32;
                const int m0 = (t >> 1) * 32;
                float4v acc = (float4v)(0.f);
                for (int k0 = 0; k0 < DIN; k0 += 64) {
                    *(short8*)&As[sr][sc] =
                        *(const short8*)(p.xcb16 + (size_t)(m0 + sr) * DIN + k0 + sc);
                    short8 wz = (short8)0;
                    int wn = n0 + sr;
                    *(short8*)&Ws[sr][sc] = (wn < 48)
                        ? *(const short8*)(xpw16 + (size_t)wn * DIN + k0 + sc) : wz;
                    __syncthreads();
                    #pragma unroll
                    for (int kk = 0; kk < 64; kk += 32) {
                        short8 a  = *(const short8*)&As[rw + m_l][kk + q * 8];
                        short8 bf = *(const short8*)&Ws[cw2 + m_l][kk + q * 8];
                        acc = __builtin_amdgcn_mfma_f32_16x16x32_bf16(a, bf, acc, 0, 0, 0);
                    }
                    __syncthreads();
                }
                int n = n0 + cw2 + m_l;
                if (n < 48) {
                    #pragma unroll
                    for (int reg = 0; reg < 4; ++reg) {
                        int m = m0 + rw + q * 4 + reg;
                        p.dbcbuf[(size_t)m * 48 + n] = acc[reg];
                    }
                }
            }
        }
        gg.sync();

        // ---- stage 4: scan summary (512 units) ----
        for (int u = blockIdx.x; u < 2 * CHK * B_; u += nb) {
            const int d = (u & 1) * 256 + tid;
            const int c = (u >> 1) & (CHK - 1);
            const int b = u >> 7;
            float A[NST], tw[DTR];
            #pragma unroll
            for (int j = 0; j < NST; ++j) A[j] = -__expf(alog[d * NST + j]);
            #pragma unroll
            for (int r = 0; r < DTR; ++r) tw[r] = dtw[d * DTR + r];
            const float tb = dtb[d];
            const int l0 = c * CT;
            const float* xp = p.xcbuf  + ((size_t)(b * L_ + l0)) * DIN + d;
            const float* bc = p.dbcbuf + ((size_t)(b * L_ + l0)) * 48;
            float h[NST];
            #pragma unroll
            for (int j = 0; j < NST; ++j) h[j] = 0.f;
            float ssum = 0.f;
            #pragma unroll 4
            for (int t = 0; t < CT; ++t) {
                const float* br = bc + t * 48;
                float acc = tb;
                #pragma unroll
                for (int r = 0; r < DTR; ++r) acc = fmaf(br[r], tw[r], acc);
                float dlt = softplusf(acc);
                float xcv = xp[t * DIN];
                float t0 = dlt * xcv;
                ssum += dlt;
                #pragma unroll
                for (int j = 0; j < NST; ++j) {
                    float dA = __expf(A[j] * dlt);
                    h[j] = fmaf(dA, h[j], t0 * br[DTR + j]);
                }
            }
            p.Sbuf[((size_t)b * CHK + c) * DIN + d] = ssum;
            float* Hp = p.Hbuf + (((size_t)b * CHK + c) * NST) * DIN + d;
            #pragma unroll
            for (int j = 0; j < NST; ++j)
                Hp[(size_t)j * DIN] = h[j];
        }
        gg.sync();

        // ---- stage 5: prefix over chunk summaries (128 units) ----
        for (int u = blockIdx.x; u < B_ * NST * DIN / 256; u += nb) {
            int idx = u * 256 + tid;
            int d = idx & (DIN - 1);
            int n = (idx >> 9) & (NST - 1);
            int b = idx >> 13;
            float A = -__expf(alog[d * NST + n]);
            float hprev = 0.f;
            const float* Sp = p.Sbuf + (size_t)b * CHK * DIN + d;
            float* Hp = p.Hbuf + (((size_t)b * CHK) * NST + n) * DIN + d;
            for (int c = 0; c < CHK; ++c) {
                float Hc = Hp[(size_t)c * NST * DIN];
                float Sc = Sp[(size_t)c * DIN];
                Hp[(size_t)c * NST * DIN] = hprev;
                hprev = fmaf(__expf(A * Sc), hprev, Hc);
            }
        }
        gg.sync();

        // ---- stage 6: scan apply (512 units) ----
        for (int u = blockIdx.x; u < 2 * CHK * B_; u += nb) {
            const int d = (u & 1) * 256 + tid;
            const int c = (u >> 1) & (CHK - 1);
            const int b = u >> 7;
            float A[NST], tw[DTR];
            #pragma unroll
            for (int j = 0; j < NST; ++j) A[j] = -__expf(alog[d * NST + j]);
            #pragma unroll
            for (int r = 0; r < DTR; ++r) tw[r] = dtw[d * DTR + r];
            const float tb = dtb[d];
            const float Dsk = dsk[d];
            const int l0 = c * CT;
            const float* xp = p.xcbuf  + ((size_t)(b * L_ + l0)) * DIN + d;
            const float* bc = p.dbcbuf + ((size_t)(b * L_ + l0)) * 48;
            const float* zp = p.xzbuf  + ((size_t)(b * L_ + l0)) * (2 * DIN) + DIN + d;
            unsigned short* yp = p.yb16 + ((size_t)(b * L_ + l0)) * DIN + d;
            float h[NST];
            const float* Hp = p.Hbuf + (((size_t)b * CHK + c) * NST) * DIN + d;
            #pragma unroll
            for (int j = 0; j < NST; ++j) h[j] = Hp[(size_t)j * DIN];
            #pragma unroll 4
            for (int t = 0; t < CT; ++t) {
                const float* br = bc + t * 48;
                float acc = tb;
                #pragma unroll
                for (int r = 0; r < DTR; ++r) acc = fmaf(br[r], tw[r], acc);
                float dlt = softplusf(acc);
                float xcv = xp[t * DIN];
                float zv  = zp[t * (2 * DIN)];
                float t0 = dlt * xcv;
                float pp = 0.f;
                #pragma unroll
                for (int j = 0; j < NST; ++j) {
                    float dA = __expf(A[j] * dlt);
                    h[j] = fmaf(dA, h[j], t0 * br[DTR + j]);
                    pp = fmaf(h[j], br[DTR + NST + j], pp);
                }
                yp[t * DIN] = f2bf((pp + xcv * Dsk) * siluf(zv));
            }
        }
        gg.sync();

        // ---- stage 7: out_proj GEMM, h += y @ W^T (64x64 tiles, 256 units) --
        {
            unsigned short (*As)[72] = (unsigned short (*)[72])smem;
            unsigned short (*Ws)[72] = (unsigned short (*)[72])(smem + 64 * 72 * 2);
            const int sr = tid >> 3;
            const int sc = (tid & 7) * 8;
            for (int t = blockIdx.x; t < 4 * 64; t += nb) {
                const int n0 = (t & 3) * 64;
                const int m0 = (t >> 2) * 64;
                float4v acc[4];
                #pragma unroll
                for (int j = 0; j < 4; ++j) acc[j] = (float4v)(0.f);
                for (int k0 = 0; k0 < DIN; k0 += 64) {
                    *(short8*)&As[sr][sc] =
                        *(const short8*)(p.yb16 + (size_t)(m0 + sr) * DIN + k0 + sc);
                    *(short8*)&As[sr + 32][sc] =
                        *(const short8*)(p.yb16 + (size_t)(m0 + sr + 32) * DIN + k0 + sc);
                    *(short8*)&Ws[sr][sc] =
                        *(const short8*)(opw16 + (size_t)(n0 + sr) * DIN + k0 + sc);
                    *(short8*)&Ws[sr + 32][sc] =
                        *(const short8*)(opw16 + (size_t)(n0 + sr + 32) * DIN + k0 + sc);
                    __syncthreads();
                    #pragma unroll
                    for (int kk = 0; kk < 64; kk += 32) {
                        short8 a = *(const short8*)&As[wave * 16 + m_l][kk + q * 8];
                        #pragma unroll
                        for (int j4 = 0; j4 < 4; ++j4) {
                            short8 bf = *(const short8*)&Ws[j4 * 16 + m_l][kk + q * 8];
                            acc[j4] = __builtin_amdgcn_mfma_f32_16x16x32_bf16(a, bf, acc[j4], 0, 0, 0);
                        }
                    }
                    __syncthreads();
                }
                #pragma unroll
                for (int j4 = 0; j4 < 4; ++j4) {
                    int n = n0 + j4 * 16 + m_l;
                    #pragma unroll
                    for (int reg = 0; reg < 4; ++reg) {
                        int m = m0 + wave * 16 + q * 4 + reg;
                        p.hbuf[(size_t)m * DM + n] += acc[j4][reg];
                    }
                }
            }
        }
        gg.sync();
    }

    // ---- stage 8a: head partial sums (64 units) ----
    for (int u = blockIdx.x; u < 64; u += nb) {
        int b = u >> 4, ch = u & 15;
        const float* hp = p.hbuf + ((size_t)(b * L_ + ch * 64)) * DM + tid;
        float s = 0.f;
        #pragma unroll 8
        for (int l = 0; l < 64; ++l) s += hp[(size_t)l * DM];
        p.partial[(size_t)u * DM + tid] = s;
    }
    gg.sync();

    // ---- stage 8b: head final (4 blocks) ----
    if ((int)blockIdx.x < B_) {
        int b = blockIdx.x;
        const float* pp = p.partial + (size_t)b * 16 * DM + tid;
        float s = 0.f;
        #pragma unroll
        for (int c = 0; c < 16; ++c) s += pp[(size_t)c * DM];
        s *= (1.f / L_);
        float a = s, qv = s * s;
        block_reduce2(a, qv);
        float mu = a * (1.f / DM);
        float var = qv * (1.f / DM) - mu * mu;
        float v = (s - mu) * rsqrtf(var + 1e-5f) * p.fnw[tid] + p.fnb[tid];
        float* pooled = (float*)smem;
        pooled[tid] = v;
        __syncthreads();
        if (tid < 10) {
            float acc = p.clb[tid];
            for (int d2 = 0; d2 < DM; ++d2)
                acc = fmaf(pooled[d2], p.clw[tid * DM + d2], acc);
            p.out[b * 10 + tid] = acc;
        }
    }
}

extern "C" void kernel_launch(void* const* d_in, const int* in_sizes, int n_in,
                              void* d_out, int out_size, void* d_ws, size_t ws_size,
                              hipStream_t stream)
{
    // workspace layout (float units), same as round 9 + partial
    float* ws     = (float*)d_ws;
    float* hbuf   = ws;                                   // B*L*DM
    float* xzbuf  = hbuf   + (size_t)B_ * L_ * DM;
    float* xcbuf  = xzbuf  + (size_t)B_ * L_ * 2 * DIN;
    float* dbcbuf = xcbuf  + (size_t)B_ * L_ * DIN;
    float* Sbuf   = dbcbuf + (size_t)B_ * L_ * 48;
    float* Hbuf   = Sbuf   + (size_t)B_ * CHK * DIN;
    float* tail   = Hbuf   + (size_t)B_ * CHK * NST * DIN;
    unsigned short* yb16  = (unsigned short*)tail;
    unsigned short* xcb16 = yb16  + (size_t)B_ * L_ * DIN;
    unsigned short* inw16 = xcb16 + (size_t)B_ * L_ * DIN;
    unsigned short* xpw16 = inw16 + (size_t)4 * 1024 * DM;
    unsigned short* opw16 = xpw16 + (size_t)4 * 48 * DIN;
    float* partial = (float*)(opw16 + (size_t)4 * DM * DIN);   // 64*DM floats

    KParams p;
    p.x    = (const float*)d_in[0];
    p.ipw  = (const float*)d_in[1];
    p.ipb  = (const float*)d_in[2];
    p.inw  = (const float*)d_in[3];
    p.cw   = (const float*)d_in[4];
    p.cb   = (const float*)d_in[5];
    p.xpw  = (const float*)d_in[6];
    p.dtw  = (const float*)d_in[7];
    p.dtb  = (const float*)d_in[8];
    p.alog = (const float*)d_in[9];
    p.dsk  = (const float*)d_in[10];
    p.opw  = (const float*)d_in[11];
    p.lnw  = (const float*)d_in[12];
    p.lnb  = (const float*)d_in[13];
    p.fnw  = (const float*)d_in[14];
    p.fnb  = (const float*)d_in[15];
    p.clw  = (const float*)d_in[16];
    p.clb  = (const float*)d_in[17];
    p.hbuf = hbuf;   p.xzbuf = xzbuf;  p.xcbuf = xcbuf;  p.dbcbuf = dbcbuf;
    p.Sbuf = Sbuf;   p.Hbuf = Hbuf;    p.partial = partial;
    p.out  = (float*)d_out;
    p.yb16 = yb16;   p.xcb16 = xcb16;
    p.inw16 = inw16; p.xpw16 = xpw16;  p.opw16 = opw16;

    int blocksPerCU = 0;
    hipOccupancyMaxActiveBlocksPerMultiprocessor(&blocksPerCU,
        reinterpret_cast<const void*>(mega_kernel), 256, 0);
    if (blocksPerCU < 1) blocksPerCU = 1;
    int grid = blocksPerCU * 256;          // 256 CUs on MI355X
    if (grid > 512) grid = 512;

    void* args[] = { &p };
    hipLaunchCooperativeKernel(reinterpret_cast<const void*>(mega_kernel),
                               dim3(grid), dim3(256), args, 0, stream);
}

// Round 11
// 421.042 us; speedup vs baseline: 3.8957x; 3.8957x over previous
//
#include <hip/hip_runtime.h>
#include <math.h>

#define B_ 4
#define L_ 1024
#define DM 256
#define DIN 512
#define NST 16
#define DTR 16
#define CHK 64          // number of chunks over L
#define CT (L_ / CHK)   // chunk length = 16

typedef short short8 __attribute__((ext_vector_type(8)));
typedef float float4v __attribute__((ext_vector_type(4)));

__device__ __forceinline__ float softplusf(float x) {
    return (x > 20.f) ? x : log1pf(__expf(x));
}
__device__ __forceinline__ float siluf(float x) {
    return x / (1.f + __expf(-x));
}
__device__ __forceinline__ unsigned short f2bf(float f) {  // RNE bf16
    unsigned int u = __float_as_uint(f);
    u = (u + 0x7fffu + ((u >> 16) & 1u)) >> 16;
    return (unsigned short)u;
}

// two-value block reduction (sum) over 256 threads = 4 waves
__device__ __forceinline__ void block_reduce2(float& a, float& q) {
    #pragma unroll
    for (int off = 32; off > 0; off >>= 1) {
        a += __shfl_down(a, off);
        q += __shfl_down(q, off);
    }
    __shared__ float sa[4], sq[4];
    int lane = threadIdx.x & 63, w = threadIdx.x >> 6;
    if (lane == 0) { sa[w] = a; sq[w] = q; }
    __syncthreads();
    a = sa[0] + sa[1] + sa[2] + sa[3];
    q = sq[0] + sq[1] + sq[2] + sq[3];
}

// ---- prologue: weight f2bf conversions + input projection in ONE dispatch --
__global__ __launch_bounds__(256) void prologue_kernel(
    const float* __restrict__ inw, int na, const float* __restrict__ xpw, int nb,
    const float* __restrict__ opw, int nc,
    unsigned short* __restrict__ oa, unsigned short* __restrict__ ob,
    unsigned short* __restrict__ oc, int nconv,
    const float* __restrict__ x, const float* __restrict__ ipw,
    const float* __restrict__ ipb, float* __restrict__ h0)
{
    if ((int)blockIdx.x < nconv) {
        int i = blockIdx.x * 256 + threadIdx.x;
        if (i < na) { oa[i] = f2bf(inw[i]); return; }
        int j = i - na;
        if (j < nb) { ob[j] = f2bf(xpw[j]); return; }
        int k = j - nb;
        if (k < nc) oc[k] = f2bf(opw[k]);
        return;
    }
    int idx = (blockIdx.x - nconv) * 256 + threadIdx.x;   // B*L*DM, d fastest
    int d = idx & (DM - 1);
    int bl = idx >> 8;
    int l = bl & (L_ - 1);
    int b = bl >> 10;
    const float* xb = x + (size_t)b * 3 * L_;
    float acc = ipb[d];
    acc = fmaf(xb[0 * L_ + l], ipw[d * 3 + 0], acc);
    acc = fmaf(xb[1 * L_ + l], ipw[d * 3 + 1], acc);
    acc = fmaf(xb[2 * L_ + l], ipw[d * 3 + 2], acc);
    h0[idx] = acc;
}

// ---- fused LN + in_proj GEMM: C[M,N] = LN(A)[M,256] @ W[N,256]^T ----
__global__ __launch_bounds__(256) void gemm_in_ln(
    const float* __restrict__ A, const unsigned short* __restrict__ W,
    const float* __restrict__ lw, const float* __restrict__ lb,
    float* __restrict__ C, int N)
{
    __shared__ unsigned short As[64][264];   // 64 rows x K=256 (+8 pad)
    __shared__ unsigned short Ws[64][72];
    const int tid = threadIdx.x;
    const int wave = tid >> 6;
    const int lane = tid & 63;
    const int m_l = lane & 15;
    const int q = lane >> 4;
    const int m0 = blockIdx.y * 64;
    const int n0 = blockIdx.x * 64;

    // ---- phase 1: layernorm rows m0..m0+63 into As (bf16), coalesced ----
    {
        const int rg = lane >> 4;
        const int c4 = lane & 15;
        #pragma unroll
        for (int p = 0; p < 4; ++p) {
            int r = p * 16 + wave * 4 + rg;
            const float* ap = A + (size_t)(m0 + r) * DM;
            float4 v[4];
            float s = 0.f, qq = 0.f;
            #pragma unroll
            for (int i = 0; i < 4; ++i) {
                v[i] = *(const float4*)(ap + i * 64 + c4 * 4);
                s  += v[i].x + v[i].y + v[i].z + v[i].w;
                qq += v[i].x * v[i].x + v[i].y * v[i].y
                    + v[i].z * v[i].z + v[i].w * v[i].w;
            }
            s += __shfl_xor(s, 1); qq += __shfl_xor(qq, 1);
            s += __shfl_xor(s, 2); qq += __shfl_xor(qq, 2);
            s += __shfl_xor(s, 4); qq += __shfl_xor(qq, 4);
            s += __shfl_xor(s, 8); qq += __shfl_xor(qq, 8);
            float mu = s * (1.f / DM);
            float var = qq * (1.f / DM) - mu * mu;
            float rs = rsqrtf(var + 1e-5f);
            #pragma unroll
            for (int i = 0; i < 4; ++i) {
                int col = i * 64 + c4 * 4;
                float4 wv = *(const float4*)(lw + col);
                float4 bv = *(const float4*)(lb + col);
                unsigned short* dst = &As[r][col];
                dst[0] = f2bf((v[i].x - mu) * rs * wv.x + bv.x);
                dst[1] = f2bf((v[i].y - mu) * rs * wv.y + bv.y);
                dst[2] = f2bf((v[i].z - mu) * rs * wv.z + bv.z);
                dst[3] = f2bf((v[i].w - mu) * rs * wv.w + bv.w);
            }
        }
    }
    __syncthreads();

    const int sr = tid >> 3;
    const int sc = (tid & 7) * 8;
    float4v acc[4];
    #pragma unroll
    for (int j = 0; j < 4; ++j) acc[j] = (float4v)(0.f);

    for (int k0 = 0; k0 < DM; k0 += 64) {
        *(short8*)&Ws[sr][sc]      = *(const short8*)(W + (size_t)(n0 + sr) * DM + k0 + sc);
        *(short8*)&Ws[sr + 32][sc] = *(const short8*)(W + (size_t)(n0 + sr + 32) * DM + k0 + sc);
        __syncthreads();
        #pragma unroll
        for (int kk = 0; kk < 64; kk += 32) {
            short8 a = *(const short8*)&As[wave * 16 + m_l][k0 + kk + q * 8];
            #pragma unroll
            for (int j4 = 0; j4 < 4; ++j4) {
                short8 b = *(const short8*)&Ws[j4 * 16 + m_l][kk + q * 8];
                acc[j4] = __builtin_amdgcn_mfma_f32_16x16x32_bf16(a, b, acc[j4], 0, 0, 0);
            }
        }
        __syncthreads();
    }
    #pragma unroll
    for (int j4 = 0; j4 < 4; ++j4) {
        int n = n0 + j4 * 16 + m_l;
        #pragma unroll
        for (int reg = 0; reg < 4; ++reg) {
            int m = m0 + wave * 16 + q * 4 + reg;
            C[(size_t)m * N + n] = acc[j4][reg];
        }
    }
}

// ---- fused conv+silu + x_proj GEMM + scan summary (one chunk per block) ----
// Block = 512 thr owns chunk c of batch b (16 rows). All deps are row-local:
// conv (registers) -> bf16 LDS A-tile -> dbc[16][48] GEMM (waves 0-2) ->
// summary scan from registers. No cross-block dependency.
__global__ __launch_bounds__(512) void conv_xproj_summary(
    const float* __restrict__ xz, const float* __restrict__ cw,
    const float* __restrict__ cb, const unsigned short* __restrict__ W,
    const float* __restrict__ A_log, const float* __restrict__ dt_w,
    const float* __restrict__ dt_b,
    float* __restrict__ dbc, float* __restrict__ S, float* __restrict__ H)
{
    __shared__ unsigned short As[CT][520];   // xc bf16, rows t, cols d (+8 pad)
    __shared__ float Dbc[CT][64];            // dbc tile (48 used)
    const int tid = threadIdx.x;             // 0..511, = channel d
    const int d = tid;
    const int c = blockIdx.x;
    const int b = blockIdx.y;
    const int l0 = c * CT;

    // --- conv + silu, rolling 4-tap window; keep fp32 in regs ---
    float xcr[CT];
    {
        const float w0 = cw[d * 4 + 0], w1 = cw[d * 4 + 1];
        const float w2 = cw[d * 4 + 2], w3 = cw[d * 4 + 3];
        const float cbv = cb[d];
        const float* xp = xz + ((size_t)(b * L_ + l0)) * (2 * DIN) + d;
        float x0 = 0.f, x1 = 0.f, x2 = 0.f;
        if (l0 >= 3) {                        // c>0 => l0>=16; c==0 => zeros
            x0 = xp[(ptrdiff_t)(-3) * (2 * DIN)];
            x1 = xp[(ptrdiff_t)(-2) * (2 * DIN)];
            x2 = xp[(ptrdiff_t)(-1) * (2 * DIN)];
        }
        #pragma unroll
        for (int t = 0; t < CT; ++t) {
            float x3 = xp[(size_t)t * (2 * DIN)];
            float a = fmaf(x0, w0, cbv);
            a = fmaf(x1, w1, a);
            a = fmaf(x2, w2, a);
            a = fmaf(x3, w3, a);
            float v = siluf(a);
            xcr[t] = v;
            As[t][d] = f2bf(v);
            x0 = x1; x1 = x2; x2 = x3;
        }
    }
    __syncthreads();

    // --- GEMM: Dbc[16][48] = As[16][512] @ W[48][512]^T (waves 0..2) ---
    {
        const int wave = tid >> 6;
        const int lane = tid & 63;
        const int m_l = lane & 15;
        const int q = lane >> 4;
        if (wave < 3) {
            float4v acc = (float4v)(0.f);
            for (int k0 = 0; k0 < DIN; k0 += 32) {
                short8 a  = *(const short8*)&As[m_l][k0 + q * 8];
                short8 bf = *(const short8*)(W + (size_t)(wave * 16 + m_l) * DIN + k0 + q * 8);
                acc = __builtin_amdgcn_mfma_f32_16x16x32_bf16(a, bf, acc, 0, 0, 0);
            }
            #pragma unroll
            for (int reg = 0; reg < 4; ++reg)
                Dbc[q * 4 + reg][wave * 16 + m_l] = acc[reg];
        }
    }
    __syncthreads();

    // --- write dbc tile to global (consumed by scan_apply) ---
    for (int i = tid; i < CT * 48; i += 512) {
        int t = i / 48, col = i - t * 48;
        dbc[((size_t)(b * L_ + l0 + t)) * 48 + col] = Dbc[t][col];
    }

    // --- summary scan: 512 threads, each owns channel d ---
    float A[NST], tw[DTR];
    #pragma unroll
    for (int j = 0; j < NST; ++j) A[j] = -__expf(A_log[d * NST + j]);
    #pragma unroll
    for (int r = 0; r < DTR; ++r) tw[r] = dt_w[d * DTR + r];
    const float tb = dt_b[d];
    float h[NST];
    #pragma unroll
    for (int j = 0; j < NST; ++j) h[j] = 0.f;
    float ssum = 0.f;
    #pragma unroll 4
    for (int t = 0; t < CT; ++t) {
        float acc = tb;
        #pragma unroll
        for (int r = 0; r < DTR; ++r) acc = fmaf(Dbc[t][r], tw[r], acc);
        float dlt = softplusf(acc);
        float t0 = dlt * xcr[t];
        ssum += dlt;
        #pragma unroll
        for (int j = 0; j < NST; ++j) {
            float dA = __expf(A[j] * dlt);
            h[j] = fmaf(dA, h[j], t0 * Dbc[t][DTR + j]);
        }
    }
    S[((size_t)b * CHK + c) * DIN + d] = ssum;
    float* Hp = H + (((size_t)b * CHK + c) * NST) * DIN + d;
    #pragma unroll
    for (int j = 0; j < NST; ++j)
        Hp[(size_t)j * DIN] = h[j];
}

// ---- prefix over chunk summaries, in place: H[c] <- h_in(c) ----
__global__ __launch_bounds__(256) void scan_prefix_kernel(
    const float* __restrict__ S, float* __restrict__ H,
    const float* __restrict__ A_log)
{
    int idx = blockIdx.x * 256 + threadIdx.x;  // B*NST*DIN, d fastest
    int d = idx & (DIN - 1);
    int n = (idx >> 9) & (NST - 1);
    int b = idx >> 13;
    float A = -__expf(A_log[d * NST + n]);
    float hprev = 0.f;
    const float* Sp = S + (size_t)b * CHK * DIN + d;
    float* Hp = H + (((size_t)b * CHK) * NST + n) * DIN + d;
    for (int c = 0; c < CHK; ++c) {
        float Hc = Hp[(size_t)c * NST * DIN];
        float Sc = Sp[(size_t)c * DIN];
        Hp[(size_t)c * NST * DIN] = hprev;
        hprev = fmaf(__expf(A * Sc), hprev, Hc);
    }
}

// ---- scan apply, conv recomputed via rolling window (no xc buffer) ----
__global__ __launch_bounds__(256) void scan_apply_kernel(
    const float* __restrict__ dbc, const float* __restrict__ xz,
    const float* __restrict__ cw, const float* __restrict__ cb,
    const float* __restrict__ A_log, const float* __restrict__ dt_w,
    const float* __restrict__ dt_b, const float* __restrict__ Dskip,
    const float* __restrict__ H, unsigned short* __restrict__ y)
{
    const int d = blockIdx.x * 256 + threadIdx.x;
    const int c = blockIdx.y;
    const int b = blockIdx.z;
    float A[NST], tw[DTR];
    #pragma unroll
    for (int j = 0; j < NST; ++j) A[j] = -__expf(A_log[d * NST + j]);
    #pragma unroll
    for (int r = 0; r < DTR; ++r) tw[r] = dt_w[d * DTR + r];
    const float tb = dt_b[d];
    const float Dsk = Dskip[d];
    const int l0 = c * CT;
    const float* bc = dbc + ((size_t)(b * L_ + l0)) * 48;
    const float* xp = xz  + ((size_t)(b * L_ + l0)) * (2 * DIN) + d;
    const float* zp = xp + DIN;
    unsigned short* yp = y + ((size_t)(b * L_ + l0)) * DIN + d;

    const float w0 = cw[d * 4 + 0], w1 = cw[d * 4 + 1];
    const float w2 = cw[d * 4 + 2], w3 = cw[d * 4 + 3];
    const float cbv = cb[d];
    float x0 = 0.f, x1 = 0.f, x2 = 0.f;
    if (l0 >= 3) {
        x0 = xp[(ptrdiff_t)(-3) * (2 * DIN)];
        x1 = xp[(ptrdiff_t)(-2) * (2 * DIN)];
        x2 = xp[(ptrdiff_t)(-1) * (2 * DIN)];
    }

    float h[NST];
    const float* Hp = H + (((size_t)b * CHK + c) * NST) * DIN + d;
    #pragma unroll
    for (int j = 0; j < NST; ++j) h[j] = Hp[(size_t)j * DIN];

    #pragma unroll 4
    for (int t = 0; t < CT; ++t) {
        float x3 = xp[(size_t)t * (2 * DIN)];
        float ca = fmaf(x0, w0, cbv);
        ca = fmaf(x1, w1, ca);
        ca = fmaf(x2, w2, ca);
        ca = fmaf(x3, w3, ca);
        float xcv = siluf(ca);
        x0 = x1; x1 = x2; x2 = x3;

        const float* br = bc + t * 48;        // block-uniform row
        float acc = tb;
        #pragma unroll
        for (int r = 0; r < DTR; ++r) acc = fmaf(br[r], tw[r], acc);
        float dlt = softplusf(acc);
        float zv  = zp[(size_t)t * (2 * DIN)];
        float t0 = dlt * xcv;
        float p = 0.f;
        #pragma unroll
        for (int j = 0; j < NST; ++j) {
            float dA = __expf(A[j] * dlt);
            h[j] = fmaf(dA, h[j], t0 * br[DTR + j]);
            p = fmaf(h[j], br[DTR + NST + j], p);
        }
        yp[t * DIN] = f2bf((p + xcv * Dsk) * siluf(zv));
    }
}

// ---- 64x64-tile bf16 MFMA GEMM (out_proj): C += A @ W^T ----
__global__ __launch_bounds__(256) void gemm_bt_bf16(
    const unsigned short* __restrict__ A, const unsigned short* __restrict__ W,
    float* C, int M, int N, int K, int lda, int accumulate)
{
    __shared__ unsigned short As[64][72];
    __shared__ unsigned short Ws[64][72];
    const int tid = threadIdx.x;
    const int wave = tid >> 6;
    const int lane = tid & 63;
    const int m_l = lane & 15;
    const int q = lane >> 4;
    const int m0 = blockIdx.y * 64;
    const int n0 = blockIdx.x * 64;
    const int sr = tid >> 3;
    const int sc = (tid & 7) * 8;

    float4v acc[4];
    #pragma unroll
    for (int j = 0; j < 4; ++j) acc[j] = (float4v)(0.f);

    for (int k0 = 0; k0 < K; k0 += 64) {
        *(short8*)&As[sr][sc]      = *(const short8*)(A + (size_t)(m0 + sr) * lda + k0 + sc);
        *(short8*)&As[sr + 32][sc] = *(const short8*)(A + (size_t)(m0 + sr + 32) * lda + k0 + sc);
        short8 wz = (short8)0;
        int wn0 = n0 + sr, wn1 = n0 + sr + 32;
        *(short8*)&Ws[sr][sc]      = (wn0 < N) ? *(const short8*)(W + (size_t)wn0 * K + k0 + sc) : wz;
        *(short8*)&Ws[sr + 32][sc] = (wn1 < N) ? *(const short8*)(W + (size_t)wn1 * K + k0 + sc) : wz;
        __syncthreads();
        #pragma unroll
        for (int kk = 0; kk < 64; kk += 32) {
            short8 a = *(const short8*)&As[wave * 16 + m_l][kk + q * 8];
            #pragma unroll
            for (int j4 = 0; j4 < 4; ++j4) {
                short8 bf = *(const short8*)&Ws[j4 * 16 + m_l][kk + q * 8];
                acc[j4] = __builtin_amdgcn_mfma_f32_16x16x32_bf16(a, bf, acc[j4], 0, 0, 0);
            }
        }
        __syncthreads();
    }
    #pragma unroll
    for (int j4 = 0; j4 < 4; ++j4) {
        int n = n0 + j4 * 16 + m_l;
        if (n < N) {
            #pragma unroll
            for (int reg = 0; reg < 4; ++reg) {
                int m = m0 + wave * 16 + q * 4 + reg;
                float* cp = C + (size_t)m * N + n;
                if (accumulate) *cp += acc[j4][reg];
                else            *cp  = acc[j4][reg];
            }
        }
    }
}

// ---- head, 2-stage ----
__global__ __launch_bounds__(256) void head_partial_kernel(
    const float* __restrict__ h, float* __restrict__ partial)
{
    int b = blockIdx.x >> 4, ch = blockIdx.x & 15, t = threadIdx.x;
    const float* hp = h + ((size_t)(b * L_ + ch * 64)) * DM + t;
    float s = 0.f;
    #pragma unroll 8
    for (int l = 0; l < 64; ++l) s += hp[(size_t)l * DM];
    partial[(size_t)blockIdx.x * DM + t] = s;
}

__global__ __launch_bounds__(256) void head_final_kernel(
    const float* __restrict__ partial, const float* __restrict__ fn_w,
    const float* __restrict__ fn_b, const float* __restrict__ cls_w,
    const float* __restrict__ cls_b, float* __restrict__ out)
{
    int b = blockIdx.x, t = threadIdx.x;
    const float* pp = partial + (size_t)b * 16 * DM + t;
    float s = 0.f;
    #pragma unroll
    for (int c = 0; c < 16; ++c) s += pp[(size_t)c * DM];
    s *= (1.f / L_);
    float a = s, q = s * s;
    block_reduce2(a, q);
    float mu = a * (1.f / DM);
    float var = q * (1.f / DM) - mu * mu;
    float v = (s - mu) * rsqrtf(var + 1e-5f) * fn_w[t] + fn_b[t];
    __shared__ float pooled[DM];
    pooled[t] = v;
    __syncthreads();
    if (t < 10) {
        float acc = cls_b[t];
        for (int d2 = 0; d2 < DM; ++d2)
            acc = fmaf(pooled[d2], cls_w[t * DM + d2], acc);
        out[b * 10 + t] = acc;
    }
}

extern "C" void kernel_launch(void* const* d_in, const int* in_sizes, int n_in,
                              void* d_out, int out_size, void* d_ws, size_t ws_size,
                              hipStream_t stream)
{
    const float* x    = (const float*)d_in[0];
    const float* ipw  = (const float*)d_in[1];
    const float* ipb  = (const float*)d_in[2];
    const float* inw  = (const float*)d_in[3];
    const float* cw   = (const float*)d_in[4];
    const float* cb   = (const float*)d_in[5];
    const float* xpw  = (const float*)d_in[6];
    const float* dtw  = (const float*)d_in[7];
    const float* dtb  = (const float*)d_in[8];
    const float* alog = (const float*)d_in[9];
    const float* dsk  = (const float*)d_in[10];
    const float* opw  = (const float*)d_in[11];
    const float* lnw  = (const float*)d_in[12];
    const float* lnb  = (const float*)d_in[13];
    const float* fnw  = (const float*)d_in[14];
    const float* fnb  = (const float*)d_in[15];
    const float* clw  = (const float*)d_in[16];
    const float* clb  = (const float*)d_in[17];

    // workspace layout (float units); xc/xcb16 eliminated by fusion
    float* ws     = (float*)d_ws;
    float* hbuf   = ws;                                   // B*L*DM
    float* xzbuf  = hbuf   + (size_t)B_ * L_ * DM;        // B*L*2*DIN
    float* dbcbuf = xzbuf  + (size_t)B_ * L_ * 2 * DIN;   // B*L*48
    float* Sbuf   = dbcbuf + (size_t)B_ * L_ * 48;        // B*CHK*DIN
    float* Hbuf   = Sbuf   + (size_t)B_ * CHK * DIN;      // B*CHK*NST*DIN
    float* tail   = Hbuf   + (size_t)B_ * CHK * NST * DIN;
    unsigned short* yb16  = (unsigned short*)tail;                  // B*L*DIN
    unsigned short* inw16 = yb16  + (size_t)B_ * L_ * DIN;// 4*1024*256
    unsigned short* xpw16 = inw16 + (size_t)4 * 1024 * DM;// 4*48*512
    unsigned short* opw16 = xpw16 + (size_t)4 * 48 * DIN; // 4*256*512
    float* partial = (float*)(opw16 + (size_t)4 * DM * DIN);   // 64*DM floats

    const int BL = B_ * L_;                               // 4096
    const int NIN = 4 * 1024 * DM, NXP = 4 * 48 * DIN, NOP = 4 * DM * DIN;
    const int NCONV = (NIN + NXP + NOP + 255) / 256;

    prologue_kernel<<<NCONV + BL * DM / 256, 256, 0, stream>>>(
        inw, NIN, xpw, NXP, opw, NOP, inw16, xpw16, opw16, NCONV,
        x, ipw, ipb, hbuf);

    for (int i = 0; i < 4; ++i) {
        // xz = LN(h) @ in_w^T   [4096,1024], LN fused
        gemm_in_ln<<<dim3(2 * DIN / 64, BL / 64), 256, 0, stream>>>(
            hbuf, inw16 + (size_t)i * 1024 * DM, lnw + i * DM, lnb + i * DM,
            xzbuf, 2 * DIN);
        // conv+silu + x_proj + scan summary, fused per chunk (256 blocks x 512)
        conv_xproj_summary<<<dim3(CHK, B_), 512, 0, stream>>>(
            xzbuf, cw + i * DIN * 4, cb + i * DIN,
            xpw16 + (size_t)i * 48 * DIN, alog + i * DIN * NST,
            dtw + i * DIN * DTR, dtb + i * DIN, dbcbuf, Sbuf, Hbuf);
        scan_prefix_kernel<<<B_ * NST * DIN / 256, 256, 0, stream>>>(
            Sbuf, Hbuf, alog + i * DIN * NST);
        // apply (conv recomputed from xz via rolling window)
        scan_apply_kernel<<<dim3(DIN / 256, CHK, B_), 256, 0, stream>>>(
            dbcbuf, xzbuf, cw + i * DIN * 4, cb + i * DIN,
            alog + i * DIN * NST, dtw + i * DIN * DTR, dtb + i * DIN,
            dsk + i * DIN, Hbuf, yb16);
        // h += y @ out_w^T   [4096,256]
        gemm_bt_bf16<<<dim3(DM / 64, BL / 64), 256, 0, stream>>>(
            yb16, opw16 + (size_t)i * DM * DIN, hbuf, BL, DM, DIN, DIN, 1);
    }

    head_partial_kernel<<<B_ * 16, 256, 0, stream>>>(hbuf, partial);
    head_final_kernel<<<B_, 256, 0, stream>>>(partial, fnw, fnb, clw, clb,
                                              (float*)d_out);
}

// Round 12
// 385.629 us; speedup vs baseline: 4.2534x; 1.0918x over previous
//
#include <hip/hip_runtime.h>
#include <math.h>

#define B_ 4
#define L_ 1024
#define DM 256
#define DIN 512
#define NST 16
#define DTR 16
#define CHK 64          // number of chunks over L
#define CT (L_ / CHK)   // chunk length = 16

typedef short short8 __attribute__((ext_vector_type(8)));
typedef float float4v __attribute__((ext_vector_type(4)));

__device__ __forceinline__ float softplusf(float x) {
    return (x > 20.f) ? x : log1pf(__expf(x));
}
__device__ __forceinline__ float siluf(float x) {
    return x / (1.f + __expf(-x));
}
__device__ __forceinline__ unsigned short f2bf(float f) {  // RNE bf16
    unsigned int u = __float_as_uint(f);
    u = (u + 0x7fffu + ((u >> 16) & 1u)) >> 16;
    return (unsigned short)u;
}

// two-value block reduction (sum) over 256 threads = 4 waves
__device__ __forceinline__ void block_reduce2(float& a, float& q) {
    #pragma unroll
    for (int off = 32; off > 0; off >>= 1) {
        a += __shfl_down(a, off);
        q += __shfl_down(q, off);
    }
    __shared__ float sa[4], sq[4];
    int lane = threadIdx.x & 63, w = threadIdx.x >> 6;
    if (lane == 0) { sa[w] = a; sq[w] = q; }
    __syncthreads();
    a = sa[0] + sa[1] + sa[2] + sa[3];
    q = sq[0] + sq[1] + sq[2] + sq[3];
}

// ---- prologue: weight f2bf conversions + input projection in ONE dispatch --
__global__ __launch_bounds__(256) void prologue_kernel(
    const float* __restrict__ inw, int na, const float* __restrict__ xpw, int nb,
    const float* __restrict__ opw, int nc,
    unsigned short* __restrict__ oa, unsigned short* __restrict__ ob,
    unsigned short* __restrict__ oc, int nconv,
    const float* __restrict__ x, const float* __restrict__ ipw,
    const float* __restrict__ ipb, float* __restrict__ h0)
{
    if ((int)blockIdx.x < nconv) {
        int i = blockIdx.x * 256 + threadIdx.x;
        if (i < na) { oa[i] = f2bf(inw[i]); return; }
        int j = i - na;
        if (j < nb) { ob[j] = f2bf(xpw[j]); return; }
        int k = j - nb;
        if (k < nc) oc[k] = f2bf(opw[k]);
        return;
    }
    int idx = (blockIdx.x - nconv) * 256 + threadIdx.x;   // B*L*DM, d fastest
    int d = idx & (DM - 1);
    int bl = idx >> 8;
    int l = bl & (L_ - 1);
    int b = bl >> 10;
    const float* xb = x + (size_t)b * 3 * L_;
    float acc = ipb[d];
    acc = fmaf(xb[0 * L_ + l], ipw[d * 3 + 0], acc);
    acc = fmaf(xb[1 * L_ + l], ipw[d * 3 + 1], acc);
    acc = fmaf(xb[2 * L_ + l], ipw[d * 3 + 2], acc);
    h0[idx] = acc;
}

// ---- fused LN + in_proj GEMM: C[M,N] = LN(A)[M,256] @ W[N,256]^T ----
__global__ __launch_bounds__(256) void gemm_in_ln(
    const float* __restrict__ A, const unsigned short* __restrict__ W,
    const float* __restrict__ lw, const float* __restrict__ lb,
    float* __restrict__ C, int N)
{
    __shared__ unsigned short As[64][264];   // 64 rows x K=256 (+8 pad)
    __shared__ unsigned short Ws[64][72];
    const int tid = threadIdx.x;
    const int wave = tid >> 6;
    const int lane = tid & 63;
    const int m_l = lane & 15;
    const int q = lane >> 4;
    const int m0 = blockIdx.y * 64;
    const int n0 = blockIdx.x * 64;

    // ---- phase 1: layernorm rows m0..m0+63 into As (bf16), coalesced ----
    {
        const int rg = lane >> 4;
        const int c4 = lane & 15;
        #pragma unroll
        for (int p = 0; p < 4; ++p) {
            int r = p * 16 + wave * 4 + rg;
            const float* ap = A + (size_t)(m0 + r) * DM;
            float4 v[4];
            float s = 0.f, qq = 0.f;
            #pragma unroll
            for (int i = 0; i < 4; ++i) {
                v[i] = *(const float4*)(ap + i * 64 + c4 * 4);
                s  += v[i].x + v[i].y + v[i].z + v[i].w;
                qq += v[i].x * v[i].x + v[i].y * v[i].y
                    + v[i].z * v[i].z + v[i].w * v[i].w;
            }
            s += __shfl_xor(s, 1); qq += __shfl_xor(qq, 1);
            s += __shfl_xor(s, 2); qq += __shfl_xor(qq, 2);
            s += __shfl_xor(s, 4); qq += __shfl_xor(qq, 4);
            s += __shfl_xor(s, 8); qq += __shfl_xor(qq, 8);
            float mu = s * (1.f / DM);
            float var = qq * (1.f / DM) - mu * mu;
            float rs = rsqrtf(var + 1e-5f);
            #pragma unroll
            for (int i = 0; i < 4; ++i) {
                int col = i * 64 + c4 * 4;
                float4 wv = *(const float4*)(lw + col);
                float4 bv = *(const float4*)(lb + col);
                unsigned short* dst = &As[r][col];
                dst[0] = f2bf((v[i].x - mu) * rs * wv.x + bv.x);
                dst[1] = f2bf((v[i].y - mu) * rs * wv.y + bv.y);
                dst[2] = f2bf((v[i].z - mu) * rs * wv.z + bv.z);
                dst[3] = f2bf((v[i].w - mu) * rs * wv.w + bv.w);
            }
        }
    }
    __syncthreads();

    const int sr = tid >> 3;
    const int sc = (tid & 7) * 8;
    float4v acc[4];
    #pragma unroll
    for (int j = 0; j < 4; ++j) acc[j] = (float4v)(0.f);

    for (int k0 = 0; k0 < DM; k0 += 64) {
        *(short8*)&Ws[sr][sc]      = *(const short8*)(W + (size_t)(n0 + sr) * DM + k0 + sc);
        *(short8*)&Ws[sr + 32][sc] = *(const short8*)(W + (size_t)(n0 + sr + 32) * DM + k0 + sc);
        __syncthreads();
        #pragma unroll
        for (int kk = 0; kk < 64; kk += 32) {
            short8 a = *(const short8*)&As[wave * 16 + m_l][k0 + kk + q * 8];
            #pragma unroll
            for (int j4 = 0; j4 < 4; ++j4) {
                short8 b = *(const short8*)&Ws[j4 * 16 + m_l][kk + q * 8];
                acc[j4] = __builtin_amdgcn_mfma_f32_16x16x32_bf16(a, b, acc[j4], 0, 0, 0);
            }
        }
        __syncthreads();
    }
    #pragma unroll
    for (int j4 = 0; j4 < 4; ++j4) {
        int n = n0 + j4 * 16 + m_l;
        #pragma unroll
        for (int reg = 0; reg < 4; ++reg) {
            int m = m0 + wave * 16 + q * 4 + reg;
            C[(size_t)m * N + n] = acc[j4][reg];
        }
    }
}

// ---- fused conv+silu + x_proj GEMM + scan summary (one chunk per block) ----
__global__ __launch_bounds__(512) void conv_xproj_summary(
    const float* __restrict__ xz, const float* __restrict__ cw,
    const float* __restrict__ cb, const unsigned short* __restrict__ W,
    const float* __restrict__ A_log, const float* __restrict__ dt_w,
    const float* __restrict__ dt_b,
    float* __restrict__ dbc, float* __restrict__ S, float* __restrict__ H)
{
    __shared__ unsigned short As[CT][520];   // xc bf16, rows t, cols d (+8 pad)
    __shared__ float Dbc[CT][64];            // dbc tile (48 used)
    const int tid = threadIdx.x;             // 0..511, = channel d
    const int d = tid;
    const int c = blockIdx.x;
    const int b = blockIdx.y;
    const int l0 = c * CT;

    // --- conv + silu, rolling 4-tap window; keep fp32 in regs ---
    float xcr[CT];
    {
        const float w0 = cw[d * 4 + 0], w1 = cw[d * 4 + 1];
        const float w2 = cw[d * 4 + 2], w3 = cw[d * 4 + 3];
        const float cbv = cb[d];
        const float* xp = xz + ((size_t)(b * L_ + l0)) * (2 * DIN) + d;
        float x0 = 0.f, x1 = 0.f, x2 = 0.f;
        if (l0 >= 3) {
            x0 = xp[(ptrdiff_t)(-3) * (2 * DIN)];
            x1 = xp[(ptrdiff_t)(-2) * (2 * DIN)];
            x2 = xp[(ptrdiff_t)(-1) * (2 * DIN)];
        }
        #pragma unroll
        for (int t = 0; t < CT; ++t) {
            float x3 = xp[(size_t)t * (2 * DIN)];
            float a = fmaf(x0, w0, cbv);
            a = fmaf(x1, w1, a);
            a = fmaf(x2, w2, a);
            a = fmaf(x3, w3, a);
            float v = siluf(a);
            xcr[t] = v;
            As[t][d] = f2bf(v);
            x0 = x1; x1 = x2; x2 = x3;
        }
    }
    __syncthreads();

    // --- GEMM: Dbc[16][48] = As[16][512] @ W[48][512]^T (waves 0..2) ---
    {
        const int wave = tid >> 6;
        const int lane = tid & 63;
        const int m_l = lane & 15;
        const int q = lane >> 4;
        if (wave < 3) {
            float4v acc = (float4v)(0.f);
            for (int k0 = 0; k0 < DIN; k0 += 32) {
                short8 a  = *(const short8*)&As[m_l][k0 + q * 8];
                short8 bf = *(const short8*)(W + (size_t)(wave * 16 + m_l) * DIN + k0 + q * 8);
                acc = __builtin_amdgcn_mfma_f32_16x16x32_bf16(a, bf, acc, 0, 0, 0);
            }
            #pragma unroll
            for (int reg = 0; reg < 4; ++reg)
                Dbc[q * 4 + reg][wave * 16 + m_l] = acc[reg];
        }
    }
    __syncthreads();

    // --- write dbc tile to global (consumed by scan_apply_out) ---
    for (int i = tid; i < CT * 48; i += 512) {
        int t = i / 48, col = i - t * 48;
        dbc[((size_t)(b * L_ + l0 + t)) * 48 + col] = Dbc[t][col];
    }

    // --- summary scan: 512 threads, each owns channel d ---
    float A[NST], tw[DTR];
    #pragma unroll
    for (int j = 0; j < NST; ++j) A[j] = -__expf(A_log[d * NST + j]);
    #pragma unroll
    for (int r = 0; r < DTR; ++r) tw[r] = dt_w[d * DTR + r];
    const float tb = dt_b[d];
    float h[NST];
    #pragma unroll
    for (int j = 0; j < NST; ++j) h[j] = 0.f;
    float ssum = 0.f;
    #pragma unroll 4
    for (int t = 0; t < CT; ++t) {
        float acc = tb;
        #pragma unroll
        for (int r = 0; r < DTR; ++r) acc = fmaf(Dbc[t][r], tw[r], acc);
        float dlt = softplusf(acc);
        float t0 = dlt * xcr[t];
        ssum += dlt;
        #pragma unroll
        for (int j = 0; j < NST; ++j) {
            float dA = __expf(A[j] * dlt);
            h[j] = fmaf(dA, h[j], t0 * Dbc[t][DTR + j]);
        }
    }
    S[((size_t)b * CHK + c) * DIN + d] = ssum;
    float* Hp = H + (((size_t)b * CHK + c) * NST) * DIN + d;
    #pragma unroll
    for (int j = 0; j < NST; ++j)
        Hp[(size_t)j * DIN] = h[j];
}

// ---- prefix over chunk summaries, in place: H[c] <- h_in(c) ----
__global__ __launch_bounds__(256) void scan_prefix_kernel(
    const float* __restrict__ S, float* __restrict__ H,
    const float* __restrict__ A_log)
{
    int idx = blockIdx.x * 256 + threadIdx.x;  // B*NST*DIN, d fastest
    int d = idx & (DIN - 1);
    int n = (idx >> 9) & (NST - 1);
    int b = idx >> 13;
    float A = -__expf(A_log[d * NST + n]);
    float hprev = 0.f;
    const float* Sp = S + (size_t)b * CHK * DIN + d;
    float* Hp = H + (((size_t)b * CHK) * NST + n) * DIN + d;
    for (int c = 0; c < CHK; ++c) {
        float Hc = Hp[(size_t)c * NST * DIN];
        float Sc = Sp[(size_t)c * DIN];
        Hp[(size_t)c * NST * DIN] = hprev;
        hprev = fmaf(__expf(A * Sc), hprev, Hc);
    }
}

// ---- fused scan apply + out_proj (one chunk per block, 512 thr) ----
// Phase A: apply for the chunk's 16 rows x 512 channels; y -> LDS bf16.
// Phase B: h[16 rows][256] += Ys[16][512] @ Wout[256][512]^T — K-reduction
// is over channels, entirely block-local; the 16 h rows are chunk-exclusive.
__global__ __launch_bounds__(512) void scan_apply_out(
    const float* __restrict__ dbc, const float* __restrict__ xz,
    const float* __restrict__ cw, const float* __restrict__ cb,
    const float* __restrict__ A_log, const float* __restrict__ dt_w,
    const float* __restrict__ dt_b, const float* __restrict__ Dskip,
    const float* __restrict__ H, const unsigned short* __restrict__ Wout,
    float* __restrict__ hbuf)
{
    __shared__ unsigned short Ys[CT][520];   // y bf16, rows t, cols d (+8 pad)
    const int tid = threadIdx.x;             // = channel d in phase A
    const int d = tid;
    const int c = blockIdx.x;
    const int b = blockIdx.y;
    const int l0 = c * CT;

    // --- phase A: scan apply (conv recomputed via rolling window) ---
    {
        float A[NST], tw[DTR];
        #pragma unroll
        for (int j = 0; j < NST; ++j) A[j] = -__expf(A_log[d * NST + j]);
        #pragma unroll
        for (int r = 0; r < DTR; ++r) tw[r] = dt_w[d * DTR + r];
        const float tb = dt_b[d];
        const float Dsk = Dskip[d];
        const float* bc = dbc + ((size_t)(b * L_ + l0)) * 48;
        const float* xp = xz  + ((size_t)(b * L_ + l0)) * (2 * DIN) + d;
        const float* zp = xp + DIN;

        const float w0 = cw[d * 4 + 0], w1 = cw[d * 4 + 1];
        const float w2 = cw[d * 4 + 2], w3 = cw[d * 4 + 3];
        const float cbv = cb[d];
        float x0 = 0.f, x1 = 0.f, x2 = 0.f;
        if (l0 >= 3) {
            x0 = xp[(ptrdiff_t)(-3) * (2 * DIN)];
            x1 = xp[(ptrdiff_t)(-2) * (2 * DIN)];
            x2 = xp[(ptrdiff_t)(-1) * (2 * DIN)];
        }

        float h[NST];
        const float* Hp = H + (((size_t)b * CHK + c) * NST) * DIN + d;
        #pragma unroll
        for (int j = 0; j < NST; ++j) h[j] = Hp[(size_t)j * DIN];

        #pragma unroll 4
        for (int t = 0; t < CT; ++t) {
            float x3 = xp[(size_t)t * (2 * DIN)];
            float ca = fmaf(x0, w0, cbv);
            ca = fmaf(x1, w1, ca);
            ca = fmaf(x2, w2, ca);
            ca = fmaf(x3, w3, ca);
            float xcv = siluf(ca);
            x0 = x1; x1 = x2; x2 = x3;

            const float* br = bc + t * 48;    // block-uniform row
            float acc = tb;
            #pragma unroll
            for (int r = 0; r < DTR; ++r) acc = fmaf(br[r], tw[r], acc);
            float dlt = softplusf(acc);
            float zv  = zp[(size_t)t * (2 * DIN)];
            float t0 = dlt * xcv;
            float p = 0.f;
            #pragma unroll
            for (int j = 0; j < NST; ++j) {
                float dA = __expf(A[j] * dlt);
                h[j] = fmaf(dA, h[j], t0 * br[DTR + j]);
                p = fmaf(h[j], br[DTR + NST + j], p);
            }
            Ys[t][d] = f2bf((p + xcv * Dsk) * siluf(zv));
        }
    }
    __syncthreads();

    // --- phase B: out_proj for this chunk's 16 rows ---
    {
        const int wave = tid >> 6;
        const int lane = tid & 63;
        const int m_l = lane & 15;
        const int q = lane >> 4;
        #pragma unroll
        for (int nt = 0; nt < 2; ++nt) {
            const int n0 = (wave * 2 + nt) * 16;     // 16 n-tiles over 8 waves
            float4v acc = (float4v)(0.f);
            for (int k0 = 0; k0 < DIN; k0 += 32) {
                short8 a = *(const short8*)&Ys[m_l][k0 + q * 8];
                short8 w = *(const short8*)(Wout + (size_t)(n0 + m_l) * DIN + k0 + q * 8);
                acc = __builtin_amdgcn_mfma_f32_16x16x32_bf16(a, w, acc, 0, 0, 0);
            }
            #pragma unroll
            for (int reg = 0; reg < 4; ++reg) {
                int row = q * 4 + reg;               // t within chunk
                hbuf[((size_t)(b * L_ + l0 + row)) * DM + n0 + m_l] += acc[reg];
            }
        }
    }
}

// ---- head, 2-stage ----
__global__ __launch_bounds__(256) void head_partial_kernel(
    const float* __restrict__ h, float* __restrict__ partial)
{
    int b = blockIdx.x >> 4, ch = blockIdx.x & 15, t = threadIdx.x;
    const float* hp = h + ((size_t)(b * L_ + ch * 64)) * DM + t;
    float s = 0.f;
    #pragma unroll 8
    for (int l = 0; l < 64; ++l) s += hp[(size_t)l * DM];
    partial[(size_t)blockIdx.x * DM + t] = s;
}

__global__ __launch_bounds__(256) void head_final_kernel(
    const float* __restrict__ partial, const float* __restrict__ fn_w,
    const float* __restrict__ fn_b, const float* __restrict__ cls_w,
    const float* __restrict__ cls_b, float* __restrict__ out)
{
    int b = blockIdx.x, t = threadIdx.x;
    const float* pp = partial + (size_t)b * 16 * DM + t;
    float s = 0.f;
    #pragma unroll
    for (int c = 0; c < 16; ++c) s += pp[(size_t)c * DM];
    s *= (1.f / L_);
    float a = s, q = s * s;
    block_reduce2(a, q);
    float mu = a * (1.f / DM);
    float var = q * (1.f / DM) - mu * mu;
    float v = (s - mu) * rsqrtf(var + 1e-5f) * fn_w[t] + fn_b[t];
    __shared__ float pooled[DM];
    pooled[t] = v;
    __syncthreads();
    if (t < 10) {
        float acc = cls_b[t];
        for (int d2 = 0; d2 < DM; ++d2)
            acc = fmaf(pooled[d2], cls_w[t * DM + d2], acc);
        out[b * 10 + t] = acc;
    }
}

extern "C" void kernel_launch(void* const* d_in, const int* in_sizes, int n_in,
                              void* d_out, int out_size, void* d_ws, size_t ws_size,
                              hipStream_t stream)
{
    const float* x    = (const float*)d_in[0];
    const float* ipw  = (const float*)d_in[1];
    const float* ipb  = (const float*)d_in[2];
    const float* inw  = (const float*)d_in[3];
    const float* cw   = (const float*)d_in[4];
    const float* cb   = (const float*)d_in[5];
    const float* xpw  = (const float*)d_in[6];
    const float* dtw  = (const float*)d_in[7];
    const float* dtb  = (const float*)d_in[8];
    const float* alog = (const float*)d_in[9];
    const float* dsk  = (const float*)d_in[10];
    const float* opw  = (const float*)d_in[11];
    const float* lnw  = (const float*)d_in[12];
    const float* lnb  = (const float*)d_in[13];
    const float* fnw  = (const float*)d_in[14];
    const float* fnb  = (const float*)d_in[15];
    const float* clw  = (const float*)d_in[16];
    const float* clb  = (const float*)d_in[17];

    // workspace layout (float units); yb16 eliminated by apply+out fusion
    float* ws     = (float*)d_ws;
    float* hbuf   = ws;                                   // B*L*DM
    float* xzbuf  = hbuf   + (size_t)B_ * L_ * DM;        // B*L*2*DIN
    float* dbcbuf = xzbuf  + (size_t)B_ * L_ * 2 * DIN;   // B*L*48
    float* Sbuf   = dbcbuf + (size_t)B_ * L_ * 48;        // B*CHK*DIN
    float* Hbuf   = Sbuf   + (size_t)B_ * CHK * DIN;      // B*CHK*NST*DIN
    float* tail   = Hbuf   + (size_t)B_ * CHK * NST * DIN;
    unsigned short* inw16 = (unsigned short*)tail;        // 4*1024*256
    unsigned short* xpw16 = inw16 + (size_t)4 * 1024 * DM;// 4*48*512
    unsigned short* opw16 = xpw16 + (size_t)4 * 48 * DIN; // 4*256*512
    float* partial = (float*)(opw16 + (size_t)4 * DM * DIN);   // 64*DM floats

    const int BL = B_ * L_;                               // 4096
    const int NIN = 4 * 1024 * DM, NXP = 4 * 48 * DIN, NOP = 4 * DM * DIN;
    const int NCONV = (NIN + NXP + NOP + 255) / 256;

    prologue_kernel<<<NCONV + BL * DM / 256, 256, 0, stream>>>(
        inw, NIN, xpw, NXP, opw, NOP, inw16, xpw16, opw16, NCONV,
        x, ipw, ipb, hbuf);

    for (int i = 0; i < 4; ++i) {
        // xz = LN(h) @ in_w^T   [4096,1024], LN fused
        gemm_in_ln<<<dim3(2 * DIN / 64, BL / 64), 256, 0, stream>>>(
            hbuf, inw16 + (size_t)i * 1024 * DM, lnw + i * DM, lnb + i * DM,
            xzbuf, 2 * DIN);
        // conv+silu + x_proj + scan summary, fused per chunk (256 blocks x 512)
        conv_xproj_summary<<<dim3(CHK, B_), 512, 0, stream>>>(
            xzbuf, cw + i * DIN * 4, cb + i * DIN,
            xpw16 + (size_t)i * 48 * DIN, alog + i * DIN * NST,
            dtw + i * DIN * DTR, dtb + i * DIN, dbcbuf, Sbuf, Hbuf);
        scan_prefix_kernel<<<B_ * NST * DIN / 256, 256, 0, stream>>>(
            Sbuf, Hbuf, alog + i * DIN * NST);
        // apply + out_proj fused per chunk (256 blocks x 512)
        scan_apply_out<<<dim3(CHK, B_), 512, 0, stream>>>(
            dbcbuf, xzbuf, cw + i * DIN * 4, cb + i * DIN,
            alog + i * DIN * NST, dtw + i * DIN * DTR, dtb + i * DIN,
            dsk + i * DIN, Hbuf, opw16 + (size_t)i * DM * DIN, hbuf);
    }

    head_partial_kernel<<<B_ * 16, 256, 0, stream>>>(hbuf, partial);
    head_final_kernel<<<B_, 256, 0, stream>>>(partial, fnw, fnb, clw, clb,
                                              (float*)d_out);
}

// Round 13
// 385.579 us; speedup vs baseline: 4.2540x; 1.0001x over previous
//
#include <hip/hip_runtime.h>
#include <math.h>

#define B_ 4
#define L_ 1024
#define DM 256
#define DIN 512
#define NST 16
#define DTR 16
#define CHK 64          // number of chunks over L
#define CT (L_ / CHK)   // chunk length = 16

typedef short short8 __attribute__((ext_vector_type(8)));
typedef float float4v __attribute__((ext_vector_type(4)));

__device__ __forceinline__ float softplusf(float x) {
    return (x > 20.f) ? x : log1pf(__expf(x));
}
__device__ __forceinline__ float siluf(float x) {
    return x / (1.f + __expf(-x));
}
__device__ __forceinline__ unsigned short f2bf(float f) {  // RNE bf16
    unsigned int u = __float_as_uint(f);
    u = (u + 0x7fffu + ((u >> 16) & 1u)) >> 16;
    return (unsigned short)u;
}

// two-value block reduction (sum) over 256 threads = 4 waves
__device__ __forceinline__ void block_reduce2(float& a, float& q) {
    #pragma unroll
    for (int off = 32; off > 0; off >>= 1) {
        a += __shfl_down(a, off);
        q += __shfl_down(q, off);
    }
    __shared__ float sa[4], sq[4];
    int lane = threadIdx.x & 63, w = threadIdx.x >> 6;
    if (lane == 0) { sa[w] = a; sq[w] = q; }
    __syncthreads();
    a = sa[0] + sa[1] + sa[2] + sa[3];
    q = sq[0] + sq[1] + sq[2] + sq[3];
}

// ---- prologue: weight f2bf + input projection + layer-0 LN ----
// blocks [0,nconv): f2bf of inw/xpw/opw. blocks [nconv, nconv+4096):
// one block per (b,l) row: h0 row + LN(layer0) -> ln16.
__global__ __launch_bounds__(256) void prologue_kernel(
    const float* __restrict__ inw, int na, const float* __restrict__ xpw, int nb,
    const float* __restrict__ opw, int nc,
    unsigned short* __restrict__ oa, unsigned short* __restrict__ ob,
    unsigned short* __restrict__ oc, int nconv,
    const float* __restrict__ x, const float* __restrict__ ipw,
    const float* __restrict__ ipb, const float* __restrict__ lw0,
    const float* __restrict__ lb0, float* __restrict__ h0,
    unsigned short* __restrict__ ln16)
{
    if ((int)blockIdx.x < nconv) {
        int i = blockIdx.x * 256 + threadIdx.x;
        if (i < na) { oa[i] = f2bf(inw[i]); return; }
        int j = i - na;
        if (j < nb) { ob[j] = f2bf(xpw[j]); return; }
        int k = j - nb;
        if (k < nc) oc[k] = f2bf(opw[k]);
        return;
    }
    int row = blockIdx.x - nconv;                 // 0..4095 = b*L + l
    int l = row & (L_ - 1);
    int b = row >> 10;
    int d = threadIdx.x;
    const float* xb = x + (size_t)b * 3 * L_;
    float x0 = xb[l], x1 = xb[L_ + l], x2 = xb[2 * L_ + l];
    float acc = ipb[d];
    acc = fmaf(x0, ipw[d * 3 + 0], acc);
    acc = fmaf(x1, ipw[d * 3 + 1], acc);
    acc = fmaf(x2, ipw[d * 3 + 2], acc);
    float a = acc, q = acc * acc;
    block_reduce2(a, q);
    float mu = a * (1.f / DM);
    float var = q * (1.f / DM) - mu * mu;
    float rs = rsqrtf(var + 1e-5f);
    h0[(size_t)row * DM + d] = acc;
    ln16[(size_t)row * DM + d] = f2bf((acc - mu) * rs * lw0[d] + lb0[d]);
}

// ---- 64x64-tile bf16 MFMA GEMM (in_proj: C = A @ W^T, A = ln16) ----
__global__ __launch_bounds__(256) void gemm_bt_bf16(
    const unsigned short* __restrict__ A, const unsigned short* __restrict__ W,
    float* __restrict__ C, int M, int N, int K, int lda)
{
    __shared__ unsigned short As[64][72];
    __shared__ unsigned short Ws[64][72];
    const int tid = threadIdx.x;
    const int wave = tid >> 6;
    const int lane = tid & 63;
    const int m_l = lane & 15;
    const int q = lane >> 4;
    const int m0 = blockIdx.y * 64;
    const int n0 = blockIdx.x * 64;
    const int sr = tid >> 3;
    const int sc = (tid & 7) * 8;

    float4v acc[4];
    #pragma unroll
    for (int j = 0; j < 4; ++j) acc[j] = (float4v)(0.f);

    for (int k0 = 0; k0 < K; k0 += 64) {
        *(short8*)&As[sr][sc]      = *(const short8*)(A + (size_t)(m0 + sr) * lda + k0 + sc);
        *(short8*)&As[sr + 32][sc] = *(const short8*)(A + (size_t)(m0 + sr + 32) * lda + k0 + sc);
        *(short8*)&Ws[sr][sc]      = *(const short8*)(W + (size_t)(n0 + sr) * K + k0 + sc);
        *(short8*)&Ws[sr + 32][sc] = *(const short8*)(W + (size_t)(n0 + sr + 32) * K + k0 + sc);
        __syncthreads();
        #pragma unroll
        for (int kk = 0; kk < 64; kk += 32) {
            short8 a = *(const short8*)&As[wave * 16 + m_l][kk + q * 8];
            #pragma unroll
            for (int j4 = 0; j4 < 4; ++j4) {
                short8 bf = *(const short8*)&Ws[j4 * 16 + m_l][kk + q * 8];
                acc[j4] = __builtin_amdgcn_mfma_f32_16x16x32_bf16(a, bf, acc[j4], 0, 0, 0);
            }
        }
        __syncthreads();
    }
    #pragma unroll
    for (int j4 = 0; j4 < 4; ++j4) {
        int n = n0 + j4 * 16 + m_l;
        #pragma unroll
        for (int reg = 0; reg < 4; ++reg) {
            int m = m0 + wave * 16 + q * 4 + reg;
            C[(size_t)m * N + n] = acc[j4][reg];
        }
    }
}

// ---- fused conv+silu + x_proj GEMM + scan summary (one chunk per block) ----
__global__ __launch_bounds__(512) void conv_xproj_summary(
    const float* __restrict__ xz, const float* __restrict__ cw,
    const float* __restrict__ cb, const unsigned short* __restrict__ W,
    const float* __restrict__ A_log, const float* __restrict__ dt_w,
    const float* __restrict__ dt_b,
    float* __restrict__ dbc, float* __restrict__ S, float* __restrict__ H)
{
    __shared__ unsigned short As[CT][520];   // xc bf16, rows t, cols d (+8 pad)
    __shared__ float Dbc[CT][64];            // dbc tile (48 used)
    const int tid = threadIdx.x;             // 0..511, = channel d
    const int d = tid;
    const int c = blockIdx.x;
    const int b = blockIdx.y;
    const int l0 = c * CT;

    // --- conv + silu, rolling 4-tap window; keep fp32 in regs ---
    float xcr[CT];
    {
        const float w0 = cw[d * 4 + 0], w1 = cw[d * 4 + 1];
        const float w2 = cw[d * 4 + 2], w3 = cw[d * 4 + 3];
        const float cbv = cb[d];
        const float* xp = xz + ((size_t)(b * L_ + l0)) * (2 * DIN) + d;
        float x0 = 0.f, x1 = 0.f, x2 = 0.f;
        if (l0 >= 3) {
            x0 = xp[(ptrdiff_t)(-3) * (2 * DIN)];
            x1 = xp[(ptrdiff_t)(-2) * (2 * DIN)];
            x2 = xp[(ptrdiff_t)(-1) * (2 * DIN)];
        }
        #pragma unroll
        for (int t = 0; t < CT; ++t) {
            float x3 = xp[(size_t)t * (2 * DIN)];
            float a = fmaf(x0, w0, cbv);
            a = fmaf(x1, w1, a);
            a = fmaf(x2, w2, a);
            a = fmaf(x3, w3, a);
            float v = siluf(a);
            xcr[t] = v;
            As[t][d] = f2bf(v);
            x0 = x1; x1 = x2; x2 = x3;
        }
    }
    __syncthreads();

    // --- GEMM: Dbc[16][48] = As[16][512] @ W[48][512]^T (waves 0..2) ---
    {
        const int wave = tid >> 6;
        const int lane = tid & 63;
        const int m_l = lane & 15;
        const int q = lane >> 4;
        if (wave < 3) {
            float4v acc = (float4v)(0.f);
            for (int k0 = 0; k0 < DIN; k0 += 32) {
                short8 a  = *(const short8*)&As[m_l][k0 + q * 8];
                short8 bf = *(const short8*)(W + (size_t)(wave * 16 + m_l) * DIN + k0 + q * 8);
                acc = __builtin_amdgcn_mfma_f32_16x16x32_bf16(a, bf, acc, 0, 0, 0);
            }
            #pragma unroll
            for (int reg = 0; reg < 4; ++reg)
                Dbc[q * 4 + reg][wave * 16 + m_l] = acc[reg];
        }
    }
    __syncthreads();

    // --- write dbc tile to global (consumed by scan_apply_out) ---
    for (int i = tid; i < CT * 48; i += 512) {
        int t = i / 48, col = i - t * 48;
        dbc[((size_t)(b * L_ + l0 + t)) * 48 + col] = Dbc[t][col];
    }

    // --- summary scan: 512 threads, each owns channel d ---
    float A[NST], tw[DTR];
    #pragma unroll
    for (int j = 0; j < NST; ++j) A[j] = -__expf(A_log[d * NST + j]);
    #pragma unroll
    for (int r = 0; r < DTR; ++r) tw[r] = dt_w[d * DTR + r];
    const float tb = dt_b[d];
    float h[NST];
    #pragma unroll
    for (int j = 0; j < NST; ++j) h[j] = 0.f;
    float ssum = 0.f;
    #pragma unroll 4
    for (int t = 0; t < CT; ++t) {
        float acc = tb;
        #pragma unroll
        for (int r = 0; r < DTR; ++r) acc = fmaf(Dbc[t][r], tw[r], acc);
        float dlt = softplusf(acc);
        float t0 = dlt * xcr[t];
        ssum += dlt;
        #pragma unroll
        for (int j = 0; j < NST; ++j) {
            float dA = __expf(A[j] * dlt);
            h[j] = fmaf(dA, h[j], t0 * Dbc[t][DTR + j]);
        }
    }
    S[((size_t)b * CHK + c) * DIN + d] = ssum;
    float* Hp = H + (((size_t)b * CHK + c) * NST) * DIN + d;
    #pragma unroll
    for (int j = 0; j < NST; ++j)
        Hp[(size_t)j * DIN] = h[j];
}

// ---- prefix over chunk summaries, in place: H[c] <- h_in(c) ----
__global__ __launch_bounds__(256) void scan_prefix_kernel(
    const float* __restrict__ S, float* __restrict__ H,
    const float* __restrict__ A_log)
{
    int idx = blockIdx.x * 256 + threadIdx.x;  // B*NST*DIN, d fastest
    int d = idx & (DIN - 1);
    int n = (idx >> 9) & (NST - 1);
    int b = idx >> 13;
    float A = -__expf(A_log[d * NST + n]);
    float hprev = 0.f;
    const float* Sp = S + (size_t)b * CHK * DIN + d;
    float* Hp = H + (((size_t)b * CHK) * NST + n) * DIN + d;
    for (int c = 0; c < CHK; ++c) {
        float Hc = Hp[(size_t)c * NST * DIN];
        float Sc = Sp[(size_t)c * DIN];
        Hp[(size_t)c * NST * DIN] = hprev;
        hprev = fmaf(__expf(A * Sc), hprev, Hc);
    }
}

// ---- fused scan apply + out_proj + residual + next-layer LN ----
// One chunk (16 rows) per block, 512 thr.
// Phase A: apply -> y bf16 in LDS.  Phase B: hrow = h_prev + y @ Wout^T (LDS).
// Phase C: last==0 -> write hbuf + LN(next layer) -> ln16;
//          last==1 -> column sums of hrow -> chunkpartial (mean-pool input).
__global__ __launch_bounds__(512) void scan_apply_out(
    const float* __restrict__ dbc, const float* __restrict__ xz,
    const float* __restrict__ cw, const float* __restrict__ cb,
    const float* __restrict__ A_log, const float* __restrict__ dt_w,
    const float* __restrict__ dt_b, const float* __restrict__ Dskip,
    const float* __restrict__ H, const unsigned short* __restrict__ Wout,
    float* __restrict__ hbuf, const float* __restrict__ nlw,
    const float* __restrict__ nlb, unsigned short* __restrict__ ln16,
    float* __restrict__ chunkpartial, int last)
{
    __shared__ unsigned short Ys[CT][520];   // y bf16 (+8 pad)
    __shared__ float hrow[CT][264];          // h rows fp32 (+8 pad)
    const int tid = threadIdx.x;             // = channel d in phase A
    const int d = tid;
    const int c = blockIdx.x;
    const int b = blockIdx.y;
    const int l0 = c * CT;

    // --- phase A: scan apply (conv recomputed via rolling window) ---
    {
        float A[NST], tw[DTR];
        #pragma unroll
        for (int j = 0; j < NST; ++j) A[j] = -__expf(A_log[d * NST + j]);
        #pragma unroll
        for (int r = 0; r < DTR; ++r) tw[r] = dt_w[d * DTR + r];
        const float tb = dt_b[d];
        const float Dsk = Dskip[d];
        const float* bc = dbc + ((size_t)(b * L_ + l0)) * 48;
        const float* xp = xz  + ((size_t)(b * L_ + l0)) * (2 * DIN) + d;
        const float* zp = xp + DIN;

        const float w0 = cw[d * 4 + 0], w1 = cw[d * 4 + 1];
        const float w2 = cw[d * 4 + 2], w3 = cw[d * 4 + 3];
        const float cbv = cb[d];
        float x0 = 0.f, x1 = 0.f, x2 = 0.f;
        if (l0 >= 3) {
            x0 = xp[(ptrdiff_t)(-3) * (2 * DIN)];
            x1 = xp[(ptrdiff_t)(-2) * (2 * DIN)];
            x2 = xp[(ptrdiff_t)(-1) * (2 * DIN)];
        }

        float h[NST];
        const float* Hp = H + (((size_t)b * CHK + c) * NST) * DIN + d;
        #pragma unroll
        for (int j = 0; j < NST; ++j) h[j] = Hp[(size_t)j * DIN];

        #pragma unroll 4
        for (int t = 0; t < CT; ++t) {
            float x3 = xp[(size_t)t * (2 * DIN)];
            float ca = fmaf(x0, w0, cbv);
            ca = fmaf(x1, w1, ca);
            ca = fmaf(x2, w2, ca);
            ca = fmaf(x3, w3, ca);
            float xcv = siluf(ca);
            x0 = x1; x1 = x2; x2 = x3;

            const float* br = bc + t * 48;    // block-uniform row
            float acc = tb;
            #pragma unroll
            for (int r = 0; r < DTR; ++r) acc = fmaf(br[r], tw[r], acc);
            float dlt = softplusf(acc);
            float zv  = zp[(size_t)t * (2 * DIN)];
            float t0 = dlt * xcv;
            float p = 0.f;
            #pragma unroll
            for (int j = 0; j < NST; ++j) {
                float dA = __expf(A[j] * dlt);
                h[j] = fmaf(dA, h[j], t0 * br[DTR + j]);
                p = fmaf(h[j], br[DTR + NST + j], p);
            }
            Ys[t][d] = f2bf((p + xcv * Dsk) * siluf(zv));
        }
    }
    __syncthreads();

    // --- load h_prev rows into LDS ---
    {
        const int row = tid >> 5;             // 16 rows x 32 threads
        const int col0 = (tid & 31) * 8;
        const float* hg = hbuf + ((size_t)(b * L_ + l0 + row)) * DM + col0;
        *(float4*)&hrow[row][col0]     = *(const float4*)hg;
        *(float4*)&hrow[row][col0 + 4] = *(const float4*)(hg + 4);
    }
    __syncthreads();

    // --- phase B: hrow += Ys @ Wout^T (8 waves x 2 n-tiles, disjoint cols) --
    {
        const int wave = tid >> 6;
        const int lane = tid & 63;
        const int m_l = lane & 15;
        const int q = lane >> 4;
        #pragma unroll
        for (int nt = 0; nt < 2; ++nt) {
            const int n0 = (wave * 2 + nt) * 16;
            float4v acc;
            #pragma unroll
            for (int reg = 0; reg < 4; ++reg)
                acc[reg] = hrow[q * 4 + reg][n0 + m_l];
            for (int k0 = 0; k0 < DIN; k0 += 32) {
                short8 a = *(const short8*)&Ys[m_l][k0 + q * 8];
                short8 w = *(const short8*)(Wout + (size_t)(n0 + m_l) * DIN + k0 + q * 8);
                acc = __builtin_amdgcn_mfma_f32_16x16x32_bf16(a, w, acc, 0, 0, 0);
            }
            #pragma unroll
            for (int reg = 0; reg < 4; ++reg)
                hrow[q * 4 + reg][n0 + m_l] = acc[reg];
        }
    }
    __syncthreads();

    // --- phase C ---
    if (!last) {
        // write h + LN with next layer's weights
        const int row = tid >> 5;
        const int c32 = tid & 31;
        const int col0 = c32 * 8;
        float v[8];
        float s = 0.f, qq = 0.f;
        #pragma unroll
        for (int i = 0; i < 8; ++i) {
            v[i] = hrow[row][col0 + i];
            s += v[i];
            qq += v[i] * v[i];
        }
        s += __shfl_xor(s, 1);  qq += __shfl_xor(qq, 1);
        s += __shfl_xor(s, 2);  qq += __shfl_xor(qq, 2);
        s += __shfl_xor(s, 4);  qq += __shfl_xor(qq, 4);
        s += __shfl_xor(s, 8);  qq += __shfl_xor(qq, 8);
        s += __shfl_xor(s, 16); qq += __shfl_xor(qq, 16);
        float mu = s * (1.f / DM);
        float var = qq * (1.f / DM) - mu * mu;
        float rs = rsqrtf(var + 1e-5f);
        float* hg = hbuf + ((size_t)(b * L_ + l0 + row)) * DM + col0;
        *(float4*)hg       = make_float4(v[0], v[1], v[2], v[3]);
        *(float4*)(hg + 4) = make_float4(v[4], v[5], v[6], v[7]);
        unsigned short* lo = ln16 + ((size_t)(b * L_ + l0 + row)) * DM + col0;
        #pragma unroll
        for (int i = 0; i < 8; ++i)
            lo[i] = f2bf((v[i] - mu) * rs * nlw[col0 + i] + nlb[col0 + i]);
    } else {
        // mean-pool partial: column sums of this chunk's 16 rows
        if (tid < DM) {
            float s = 0.f;
            #pragma unroll
            for (int t = 0; t < CT; ++t) s += hrow[t][tid];
            chunkpartial[((size_t)(b * CHK + c)) * DM + tid] = s;
        }
    }
}

// ---- head: reduce 64 chunk partials -> mean -> LN -> classifier ----
__global__ __launch_bounds__(256) void head_final_kernel(
    const float* __restrict__ chunkpartial, const float* __restrict__ fn_w,
    const float* __restrict__ fn_b, const float* __restrict__ cls_w,
    const float* __restrict__ cls_b, float* __restrict__ out)
{
    int b = blockIdx.x, t = threadIdx.x;
    const float* pp = chunkpartial + (size_t)b * CHK * DM + t;
    float s = 0.f;
    #pragma unroll 8
    for (int c = 0; c < CHK; ++c) s += pp[(size_t)c * DM];
    s *= (1.f / L_);
    float a = s, q = s * s;
    block_reduce2(a, q);
    float mu = a * (1.f / DM);
    float var = q * (1.f / DM) - mu * mu;
    float v = (s - mu) * rsqrtf(var + 1e-5f) * fn_w[t] + fn_b[t];
    __shared__ float pooled[DM];
    pooled[t] = v;
    __syncthreads();
    if (t < 10) {
        float acc = cls_b[t];
        for (int d2 = 0; d2 < DM; ++d2)
            acc = fmaf(pooled[d2], cls_w[t * DM + d2], acc);
        out[b * 10 + t] = acc;
    }
}

extern "C" void kernel_launch(void* const* d_in, const int* in_sizes, int n_in,
                              void* d_out, int out_size, void* d_ws, size_t ws_size,
                              hipStream_t stream)
{
    const float* x    = (const float*)d_in[0];
    const float* ipw  = (const float*)d_in[1];
    const float* ipb  = (const float*)d_in[2];
    const float* inw  = (const float*)d_in[3];
    const float* cw   = (const float*)d_in[4];
    const float* cb   = (const float*)d_in[5];
    const float* xpw  = (const float*)d_in[6];
    const float* dtw  = (const float*)d_in[7];
    const float* dtb  = (const float*)d_in[8];
    const float* alog = (const float*)d_in[9];
    const float* dsk  = (const float*)d_in[10];
    const float* opw  = (const float*)d_in[11];
    const float* lnw  = (const float*)d_in[12];
    const float* lnb  = (const float*)d_in[13];
    const float* fnw  = (const float*)d_in[14];
    const float* fnb  = (const float*)d_in[15];
    const float* clw  = (const float*)d_in[16];
    const float* clb  = (const float*)d_in[17];

    // workspace layout (float units)
    float* ws     = (float*)d_ws;
    float* hbuf   = ws;                                   // B*L*DM
    float* xzbuf  = hbuf   + (size_t)B_ * L_ * DM;        // B*L*2*DIN
    float* dbcbuf = xzbuf  + (size_t)B_ * L_ * 2 * DIN;   // B*L*48
    float* Sbuf   = dbcbuf + (size_t)B_ * L_ * 48;        // B*CHK*DIN
    float* Hbuf   = Sbuf   + (size_t)B_ * CHK * DIN;      // B*CHK*NST*DIN
    float* cpart  = Hbuf   + (size_t)B_ * CHK * NST * DIN;// B*CHK*DM
    float* tail   = cpart  + (size_t)B_ * CHK * DM;
    unsigned short* ln16  = (unsigned short*)tail;        // B*L*DM
    unsigned short* inw16 = ln16  + (size_t)B_ * L_ * DM; // 4*1024*256
    unsigned short* xpw16 = inw16 + (size_t)4 * 1024 * DM;// 4*48*512
    unsigned short* opw16 = xpw16 + (size_t)4 * 48 * DIN; // 4*256*512

    const int BL = B_ * L_;                               // 4096
    const int NIN = 4 * 1024 * DM, NXP = 4 * 48 * DIN, NOP = 4 * DM * DIN;
    const int NCONV = (NIN + NXP + NOP + 255) / 256;

    prologue_kernel<<<NCONV + BL, 256, 0, stream>>>(
        inw, NIN, xpw, NXP, opw, NOP, inw16, xpw16, opw16, NCONV,
        x, ipw, ipb, lnw, lnb, hbuf, ln16);

    for (int i = 0; i < 4; ++i) {
        // xz = ln16 @ in_w^T   [4096,1024] (pure GEMM; LN already done)
        gemm_bt_bf16<<<dim3(2 * DIN / 64, BL / 64), 256, 0, stream>>>(
            ln16, inw16 + (size_t)i * 1024 * DM, xzbuf, BL, 2 * DIN, DM, DM);
        // conv+silu + x_proj + scan summary, fused per chunk
        conv_xproj_summary<<<dim3(CHK, B_), 512, 0, stream>>>(
            xzbuf, cw + i * DIN * 4, cb + i * DIN,
            xpw16 + (size_t)i * 48 * DIN, alog + i * DIN * NST,
            dtw + i * DIN * DTR, dtb + i * DIN, dbcbuf, Sbuf, Hbuf);
        scan_prefix_kernel<<<B_ * NST * DIN / 256, 256, 0, stream>>>(
            Sbuf, Hbuf, alog + i * DIN * NST);
        // apply + out_proj + residual + next-layer LN (or pool partials)
        int last = (i == 3);
        const float* nlw = lnw + (last ? 0 : (i + 1) * DM);  // unused when last
        const float* nlb = lnb + (last ? 0 : (i + 1) * DM);
        scan_apply_out<<<dim3(CHK, B_), 512, 0, stream>>>(
            dbcbuf, xzbuf, cw + i * DIN * 4, cb + i * DIN,
            alog + i * DIN * NST, dtw + i * DIN * DTR, dtb + i * DIN,
            dsk + i * DIN, Hbuf, opw16 + (size_t)i * DM * DIN, hbuf,
            nlw, nlb, ln16, cpart, last);
    }

    head_final_kernel<<<B_, 256, 0, stream>>>(cpart, fnw, fnb, clw, clb,
                                              (float*)d_out);
}